// Round 19
// baseline (247.371 us; speedup 1.0000x reference)
//
#include <hip/hip_runtime.h>
#include <hip/hip_bf16.h>
#include <cstdint>
#include <cstddef>

#define N_ATOMS 10000
#define NSTRUCT 100
#define NP 4
#define NS 4
#define NF2 2560      // 4 l x 640 block-aligned symmetric-packed features
#define HID 256
#define APAD 10240    // 160 tiles of 64

// prep-kernel block ranges
#define PB_FEAT  2500                     // [0,2500): power spectrum, 4 atoms/block
#define PB_W0    (PB_FEAT + 2560)         // w0cvt: 8(n) x 80(k) x 4(p)
#define PB_W1    (PB_W0 + 256)            // w1cvt: 8 x 8 x 4
#define PB_ZERO  (PB_W1 + 300)            // fh tail rows 10000..10239
#define PB_TOTAL (PB_ZERO + 1)            // + out zero

typedef __attribute__((ext_vector_type(8))) _Float16 f16x8;
typedef __attribute__((ext_vector_type(8))) ushort u16x8;
typedef __attribute__((ext_vector_type(4))) float f32x4;

__device__ __forceinline__ float silu(float x) {
  return x / (1.f + __expf(-x));
}
__device__ __forceinline__ ushort f2h(float x) {
  _Float16 h = (_Float16)x;
  return *reinterpret_cast<ushort*>(&h);
}
// chunk c in [0,80) -> (row q, r-block b). Row q owns blocks q>>3 .. 3.
__device__ __forceinline__ void cdec(int c, int& q, int& b) {
  if (c < 32)      { q = c >> 2; b = c & 3; }
  else if (c < 56) { int x = c - 32; int j = (x * 171) >> 9; q = 8 + j; b = 1 + (x - j * 3); }
  else if (c < 72) { int x = c - 56; q = 16 + (x >> 1); b = 2 + (x & 1); }
  else             { q = 24 + (c - 72); b = 3; }
}

typedef __attribute__((address_space(3))) uint32_t lds_u32;
typedef const __attribute__((address_space(1))) uint32_t glb_u32;
__device__ __forceinline__ void glds16(const ushort* g, ushort* l) {
  __builtin_amdgcn_global_load_lds((glb_u32*)g, (lds_u32*)l, 16, 0, 0);
}

// ---------------- Kernel P: fused prep -------------------------------------
__global__ __launch_bounds__(256) void prep_kernel(
    const float* __restrict__ c0, const float* __restrict__ c1,
    const float* __restrict__ c2, const float* __restrict__ c3,
    const float* __restrict__ W0, const float* __restrict__ W1,
    ushort* __restrict__ fh, ushort* __restrict__ W0t,
    ushort* __restrict__ W1t, float* __restrict__ out) {
  __shared__ float shbuf[2048];   // feat: 4 waves x 512; cvt: 32x33
  int b = blockIdx.x;
  int tid = threadIdx.x;

  if (b < PB_FEAT) {
    // ---- power spectrum, one WAVE per atom, 5 chunks/lane ----
    int wv = tid >> 6, lane = tid & 63;
    int a = b * 4 + wv;
    float* cs = shbuf + wv * 512;
    for (int i = 0; i < 8; ++i) {
      int e = lane + i * 64;
      float v;
      if (e < 32)       v = c0[a * 32  + e];
      else if (e < 128) v = c1[a * 96  + (e - 32)];
      else if (e < 288) v = c2[a * 160 + (e - 128)];
      else              v = c3[a * 224 + (e - 288)];
      cs[e] = v;
    }
    __syncthreads();
    const float cg[4]  = {1.0f, 0.5773502691896258f, 0.4472135954999579f, 0.3779644730092272f};
    const int  off[4]  = {0, 32, 128, 288};
    const int  nm[4]   = {1, 3, 5, 7};
#pragma unroll
    for (int t = 0; t < 5; ++t) {
      int cc = lane + t * 64;           // [0,320)
      int l = cc / 80, c = cc - l * 80;
      int q, bb; cdec(c, q, bb);
      int rb = bb * 8;
      const float* base = cs + off[l];
      float s[8] = {0.f, 0.f, 0.f, 0.f, 0.f, 0.f, 0.f, 0.f};
      for (int m = 0; m < nm[l]; ++m) {
        float bq = base[m * 32 + q];
        float4 v0 = *reinterpret_cast<const float4*>(&base[m * 32 + rb]);
        float4 v1 = *reinterpret_cast<const float4*>(&base[m * 32 + rb + 4]);
        s[0] += bq * v0.x; s[1] += bq * v0.y; s[2] += bq * v0.z; s[3] += bq * v0.w;
        s[4] += bq * v1.x; s[5] += bq * v1.y; s[6] += bq * v1.z; s[7] += bq * v1.w;
      }
      u16x8 o;
#pragma unroll
      for (int u = 0; u < 8; ++u) o[u] = f2h(s[u] * cg[l]);
      *reinterpret_cast<u16x8*>(&fh[(size_t)a * NF2 + cc * 8]) = o;
    }
  } else if (b < PB_W0) {
    // ---- W0' fold -> W0t [p][h][fk] fp16 ----
    int idx = b - PB_FEAT;
    int nx = idx & 7;
    int rest = idx >> 3;
    int ky = rest % 80, p = rest / 80;
    int kt = ky * 32, nt = nx * 32;
    int lx = tid & 31, ly = tid >> 5;
    float (*t)[33] = (float(*)[33])shbuf;
    const float* src = W0 + (size_t)p * 4096 * HID;
#pragma unroll
    for (int i = 0; i < 4; ++i) {
      int kf = kt + ly + i * 8;
      int l = kf / 640, w = kf - l * 640;
      int c = w >> 3, s = w & 7;
      int q, bb; cdec(c, q, bb);
      int r = bb * 8 + s;
      float v = 0.f;
      if (r >= q) {
        v = src[(size_t)(l * 1024 + q * 32 + r) * HID + nt + lx];
        if (r > q) v += src[(size_t)(l * 1024 + r * 32 + q) * HID + nt + lx];
      }
      t[ly + i * 8][lx] = v;
    }
    __syncthreads();
    ushort* dst = W0t + (size_t)p * HID * NF2;
#pragma unroll
    for (int i = 0; i < 4; ++i)
      dst[(size_t)(nt + ly + i * 8) * NF2 + kt + lx] = f2h(t[lx][ly + i * 8]);
  } else if (b < PB_W1) {
    int idx = b - PB_W0;
    int nx = idx & 7, ky = (idx >> 3) & 7, p = idx >> 6;
    int kt = ky * 32, nt = nx * 32;
    int lx = tid & 31, ly = tid >> 5;
    float (*t)[33] = (float(*)[33])shbuf;
    const float* src = W1 + (size_t)p * HID * HID;
#pragma unroll
    for (int i = 0; i < 4; ++i)
      t[ly + i * 8][lx] = src[(size_t)(kt + ly + i * 8) * HID + nt + lx];
    __syncthreads();
    ushort* dst = W1t + (size_t)p * HID * HID;
#pragma unroll
    for (int i = 0; i < 4; ++i)
      dst[(size_t)(nt + ly + i * 8) * HID + kt + lx] = f2h(t[lx][ly + i * 8]);
  } else if (b < PB_ZERO) {
    int idx = b - PB_W1;
    size_t e = (size_t)idx * 2048 + tid * 8;
    u16x8 z = (u16x8){0, 0, 0, 0, 0, 0, 0, 0};
    *reinterpret_cast<u16x8*>(&fh[(size_t)N_ATOMS * NF2 + e]) = z;
  } else {
    if (tid < NSTRUCT) out[tid] = 0.f;
  }
}

// ---------------- Kernel F: FUSED gemm0 + layer1 + layer2 + segment-sum ----
// Block = 64 m x 256 n (one full p). Grid 640 = 160 m-tiles x 4 p, XCD-mapped
// (all 4 p of one m-group on the fh-producing XCD's L2).
// Phase 1 (K=2560 loop): A 64x32 (4KB, 32 phys rows interleaved-XOR),
//   B 256x32 (16KB, 128 phys rows interleaved-XOR); wave w owns n-quarter.
// Phase 2: pw*silu -> fp16 -> As2 (32KB, aliases staging LDS, XOR layout).
// Phase 3: layer-1 MFMA (B per-ki from L2-hot W1t), W2 dot, LDS seg-sum.
__global__ __launch_bounds__(256) void gemm_fused(
    const ushort* __restrict__ fh, const ushort* __restrict__ W0t,
    const ushort* __restrict__ W1t, const float* __restrict__ W2,
    const float* __restrict__ combW, const int* __restrict__ species,
    const int* __restrict__ sid, float* __restrict__ out) {
  __shared__ ushort smem[64 * 256];   // 32KB: phase1 As=[0,2048) Bs=[2048,10240); phase2/3 As2 all
  __shared__ float sout[NSTRUCT];
  ushort* As = smem;
  ushort* Bs = smem + 2048;
  int tid = threadIdx.x;
  int linear = blockIdx.x;                   // 0..639
  int xc = linear & 7, s = linear >> 3;      // s in [0,80)
  int p = s & 3, t = s >> 2;                 // t in [0,20)
  int bm = ((t >> 1) * 8 + xc) * 128 + (t & 1) * 64;   // 64-row m-tile
  int wid = tid >> 6, lane = tid & 63;
  int wn = wid * 64;                         // wave's n-quarter of [0,256)

  if (tid < NSTRUCT) sout[tid] = 0.f;

  // ---- phase-1 staging decode ----
  // A: 256 chunks: pr=tid>>3 (0..31), pc=tid&7; lg=pc^(pr&7): m=pr+32*(lg>>2), kc=lg&3
  int prA = tid >> 3, pcA0 = tid & 7;
  int lgA = pcA0 ^ (prA & 7);
  const ushort* gaA = fh + ((size_t)(bm + prA + 32 * (lgA >> 2)) * NF2 + (lgA & 3) * 8);
  ushort* lA = As + tid * 8;
  // B: 1024 chunks, 4/thread: d=tid+t3*256: pr=(tid>>3)+t3*32, pc=tid&7
  int lgB = pcA0 ^ ((tid >> 3) & 7);         // (pr&7) == (tid>>3)&7 for all t3
  int nB = (tid >> 3) + 128 * (lgB >> 2);
  const ushort* gaB = W0t + ((size_t)(p * 256 + nB) * NF2 + (lgB & 3) * 8);
  ushort* lB = Bs + tid * 8;

  f32x4 acc[4][4];
#pragma unroll
  for (int i = 0; i < 4; ++i)
#pragma unroll
    for (int j = 0; j < 4; ++j) acc[i][j] = (f32x4){0.f, 0.f, 0.f, 0.f};

  int mrow = lane & 15;
  int qv = lane >> 4;
  int h7 = mrow & 7;

  for (int k0 = 0; k0 < NF2; k0 += 32) {
    glds16(gaA + k0, lA);
#pragma unroll
    for (int t3 = 0; t3 < 4; ++t3)
      glds16(gaB + k0 + (size_t)t3 * 32 * NF2, lB + t3 * 2048);
    __syncthreads();

    f16x8 af[4], bf[4];
#pragma unroll
    for (int i = 0; i < 4; ++i) {
      int m = i * 16 + mrow;
      int pc = (((m >> 5) << 2) | qv) ^ (m & 7);
      af[i] = *reinterpret_cast<const f16x8*>(&As[(m & 31) * 64 + pc * 8]);
    }
#pragma unroll
    for (int j = 0; j < 4; ++j) {
      int n = wn + j * 16 + mrow;
      int pc = (((n >> 7) << 2) | qv) ^ (n & 7);
      bf[j] = *reinterpret_cast<const f16x8*>(&Bs[(n & 127) * 64 + pc * 8]);
    }
#pragma unroll
    for (int i = 0; i < 4; ++i)
#pragma unroll
      for (int j = 0; j < 4; ++j)
        acc[i][j] = __builtin_amdgcn_mfma_f32_16x16x32_f16(af[i], bf[j], acc[i][j], 0, 0, 0);
    __syncthreads();
  }

  // ---- phase-2: pw*silu -> fp16 -> As2 (XOR chunk layout) ----
  int col = lane & 15, quad = lane >> 4;
#pragma unroll
  for (int i = 0; i < 4; ++i) {
#pragma unroll
    for (int r = 0; r < 4; ++r) {
      int lm = i * 16 + quad * 4 + r;        // local m (0..63)
      int gm = bm + lm;
      bool live = (gm < N_ATOMS);
      float pw = live ? combW[p * NS + species[gm]] : 0.f;
#pragma unroll
      for (int j = 0; j < 4; ++j) {
        int lh = wn + j * 16 + col;          // 0..255
        float v = live ? silu(pw * acc[i][j][r]) : 0.f;
        int pc2 = ((lh >> 3) ^ (lm & 7));
        smem[lm * 256 + pc2 * 8 + (lh & 7)] = f2h(v);
      }
    }
  }
  __syncthreads();

  // ---- phase-3: layer-1 MFMA + W2 dot + segment-sum ----
  f32x4 acc2[4][4];
#pragma unroll
  for (int i = 0; i < 4; ++i)
#pragma unroll
    for (int j = 0; j < 4; ++j) acc2[i][j] = (f32x4){0.f, 0.f, 0.f, 0.f};

  const ushort* wb = W1t + (size_t)p * HID * HID;
#pragma unroll
  for (int ki = 0; ki < 8; ++ki) {
    f16x8 bj[4];
#pragma unroll
    for (int j = 0; j < 4; ++j)
      bj[j] = *reinterpret_cast<const f16x8*>(
          wb + (size_t)(wn + j * 16 + mrow) * 256 + ki * 32 + qv * 8);
    f16x8 af2[4];
#pragma unroll
    for (int i = 0; i < 4; ++i) {
      int lm = i * 16 + mrow;
      int pc2 = (ki * 4 + qv) ^ (lm & 7);
      af2[i] = *reinterpret_cast<const f16x8*>(&smem[lm * 256 + pc2 * 8]);
    }
#pragma unroll
    for (int i = 0; i < 4; ++i)
#pragma unroll
      for (int j = 0; j < 4; ++j)
        acc2[i][j] = __builtin_amdgcn_mfma_f32_16x16x32_f16(af2[i], bj[j], acc2[i][j], 0, 0, 0);
  }

  float w2j[4];
#pragma unroll
  for (int j = 0; j < 4; ++j) w2j[j] = W2[p * 256 + wn + j * 16 + col];
#pragma unroll
  for (int i = 0; i < 4; ++i) {
#pragma unroll
    for (int r = 0; r < 4; ++r) {
      float v = silu(acc2[i][0][r]) * w2j[0] + silu(acc2[i][1][r]) * w2j[1]
              + silu(acc2[i][2][r]) * w2j[2] + silu(acc2[i][3][r]) * w2j[3];
      v += __shfl_xor(v, 1, 64);
      v += __shfl_xor(v, 2, 64);
      v += __shfl_xor(v, 4, 64);
      v += __shfl_xor(v, 8, 64);
      if (col == 0) {
        int m = bm + i * 16 + quad * 4 + r;
        if (m < N_ATOMS) atomicAdd(&sout[sid[m]], v);
      }
    }
  }
  __syncthreads();
  if (tid < NSTRUCT) {
    float v = sout[tid];
    if (v != 0.f) atomicAdd(&out[tid], v);
  }
}

extern "C" void kernel_launch(void* const* d_in, const int* in_sizes, int n_in,
                              void* d_out, int out_size, void* d_ws, size_t ws_size,
                              hipStream_t stream) {
  const float* c0      = (const float*)d_in[0];
  const float* c1      = (const float*)d_in[1];
  const float* c2      = (const float*)d_in[2];
  const float* c3      = (const float*)d_in[3];
  const int*   species = (const int*)d_in[4];
  const int*   sid     = (const int*)d_in[5];
  const float* combW   = (const float*)d_in[6];
  const float* W0      = (const float*)d_in[7];
  const float* W1      = (const float*)d_in[8];
  const float* W2      = (const float*)d_in[9];
  float*       out     = (float*)d_out;

  // ws: fh 52.4MB | W0t 5.2MB | W1t 0.5MB = ~58MB (h0f eliminated)
  ushort* fh  = (ushort*)d_ws;
  ushort* W0t = fh  + (size_t)APAD * NF2;
  ushort* W1t = W0t + (size_t)NP * HID * NF2;

  prep_kernel<<<PB_TOTAL, 256, 0, stream>>>(c0, c1, c2, c3, W0, W1,
                                            fh, W0t, W1t, out);

  gemm_fused<<<640, 256, 0, stream>>>(fh, W0t, W1t, W2, combW, species,
                                      sid, out);
}